// Round 2
// baseline (3677.357 us; speedup 1.0000x reference)
//
#include <hip/hip_runtime.h>
#include <cstdint>

#define TT 2048
#define NH 15

typedef _Float16 half8 __attribute__((ext_vector_type(8)));
typedef float f32x4 __attribute__((ext_vector_type(4)));
typedef int int4v __attribute__((ext_vector_type(4)));

#define EXP2(x) __builtin_amdgcn_exp2f(x)
#define RCP(x) __builtin_amdgcn_rcpf(x)
#define SIGM(x) (RCP(1.0f + EXP2((x) * -1.4426950408889634f)))
#define TANHF(x) (fmaf(-2.0f, RCP(1.0f + EXP2((x) * 2.8853900817779268f)), 1.0f))
#define BPERM(addr, v) __builtin_amdgcn_ds_bpermute((addr), (v))
#define PKRTZ_I(a, b) __builtin_bit_cast(int, __builtin_amdgcn_cvt_pkrtz((a), (b)))

// MFMA formulation, layer-wavefront staggered, TWO batch tiles per wave.
// One wave = 2 x 16 batch elements, all 3 cells, all T steps.
// Per cell/tile: Z[64x16] = Wp[64x32] x V[32x16], 4x mfma_f32_16x16x32_f16.
//
// Fragment maps (m89-verified): A[m=lane&15][k=(lane>>4)*8+j];
// B[k][n=lane&15], same k map; D col=lane&15, row=(lane>>4)*4+r.
// Interleaved-K layout: k = 8q+j with
//   j<4  -> "in"  unit u = 4q+j   (prev-cell h; cell1: u15 = x)
//   j>=4 -> "own" unit u = 4q+j-4 (own recurrent h; u15 = bias 1.0)
// -> B fragment is LANE-LOCAL (no ds_bpermute): dwords =
//   { pk(in0,in1), pk(in2,in3), pk(own0,own1), pk(own2,own3) }
// Pad unit 15 state provably stays 0 (zero A row -> z=0 -> c,h stay 0).
//
// Stagger: at START of iteration i: h1f=h1(i-1), h2f=h2(i-2), h3f=h3(i-3).
// Iter i computes cell1->h1(i), cell2->h2(i-1), cell3->h3(i-2); head reads
// pre-update h3f -> out(i-3). With 2 tiles: 6 independent cell chains + 2
// head chains per iteration -> latency hiding inside one wave (we run at
// ~1 wave/SIMD; there is no TLP to be had, only ILP).
// Warmup: bias gated to 0 for cell2 (i<1) / cell3 (i<2): all-zero B keeps
// (c,h) exactly zero. Tail iters (i>=TT) compute garbage never stored.
__global__ __launch_bounds__(64) __attribute__((amdgpu_waves_per_eu(1, 1)))
void lstm3_mfma(const float* __restrict__ input,
                const float* __restrict__ w_ih1, const float* __restrict__ w_hh1,
                const float* __restrict__ b_ih1, const float* __restrict__ b_hh1,
                const float* __restrict__ w_ih2, const float* __restrict__ w_hh2,
                const float* __restrict__ b_ih2, const float* __restrict__ b_hh2,
                const float* __restrict__ w_ih3, const float* __restrict__ w_hh3,
                const float* __restrict__ b_ih3, const float* __restrict__ b_hh3,
                const float* __restrict__ w_lin, const float* __restrict__ b_lin,
                float* __restrict__ out)
{
    const int lane = threadIdx.x & 63;
    const int n = lane & 15;          // element col (within tile) AND A-row m
    const int q = lane >> 4;          // quad
    const bool q3 = (q == 3);

    // ---- A fragments (static, f16, interleaved-K layout; shared by tiles) ----
    half8 a1[4], a2[4], a3[4];
#pragma unroll
    for (int g = 0; g < 4; ++g) {
        half8 t1 = {}, t2 = {}, t3 = {};
#pragma unroll
        for (int j = 0; j < 8; ++j) {
            const int u = 4 * q + (j & 3);
            const bool isin = (j < 4);
            float v1 = 0.f, v2 = 0.f, v3 = 0.f;
            if (n < NH) {   // m = n; pad row m=15 stays zero
                const int r = g * NH + n;
                if (isin) {
                    v1 = (u < NH) ? w_hh1[r * NH + u] : w_ih1[r];   // u15 = x col
                    v2 = (u < NH) ? w_ih2[r * NH + u] : 0.f;
                    v3 = (u < NH) ? w_ih3[r * NH + u] : 0.f;
                } else {
                    v1 = (u < NH) ? 0.f               : (b_ih1[r] + b_hh1[r]);
                    v2 = (u < NH) ? w_hh2[r * NH + u] : (b_ih2[r] + b_hh2[r]);
                    v3 = (u < NH) ? w_hh3[r * NH + u] : (b_ih3[r] + b_hh3[r]);
                }
            }
            t1[j] = (_Float16)v1; t2[j] = (_Float16)v2; t3[j] = (_Float16)v3;
        }
        a1[g] = t1; a2[g] = t2; a3[g] = t3;
    }

    // head weights: partial dot over this lane's 4 units
    float wl[4];
#pragma unroll
    for (int r = 0; r < 4; ++r) {
        const int u = 4 * q + r;
        wl[r] = (u < NH) ? w_lin[u] : 0.f;
    }
    const float blv = b_lin[0];

    const f32x4 z4 = {0.f, 0.f, 0.f, 0.f};

    // ---- state: [tile][row r]; lane (q,n) holds units 4q+r of element n ----
    float h1f[2][4] = {}, c1f[2][4] = {};
    float h2f[2][4] = {}, c2f[2][4] = {};
    float h3f[2][4] = {}, c3f[2][4] = {};

    const float* xrow[2];
    float* orow[2];
#pragma unroll
    for (int b = 0; b < 2; ++b) {
        const size_t row = (size_t)(blockIdx.x * 32 + b * 16 + n);
        xrow[b] = input + row * TT;
        orow[b] = out + row * TT;
    }

    float xtile[2], xtile_n[2], xv[2], ysel[2];
#pragma unroll
    for (int b = 0; b < 2; ++b) {
        xtile[b]   = xrow[b][q];        // t = t0..t0+3 live in quads 0..3
        xtile_n[b] = xrow[b][4 + q];
        xv[b] = __int_as_float(BPERM(n * 4, __float_as_int(xtile[b])));
        ysel[b] = 0.f;
    }
    const int bcast_base = n * 4;

#pragma unroll 1
    for (int t0 = 0; t0 < TT + 4; t0 += 4) {     // i = t0+ph, runs to TT+3
#pragma unroll
        for (int ph = 0; ph < 4; ++ph) {
            const float bias2v = (ph >= 1 || t0 > 0) ? 1.0f : 0.0f;
            const float bias3v = (ph >= 2 || t0 > 0) ? 1.0f : 0.0f;

            // ---- lane-local B fragments from pre-update state (both tiles) ----
            half8 B1[2], B2[2], B3[2];
            float xv_n[2];
#pragma unroll
            for (int b = 0; b < 2; ++b) {
                // pipelined broadcast of x(i+1) (used next iteration)
                const float xsrc = (ph == 3) ? xtile_n[b] : xtile[b];
                xv_n[b] = __int_as_float(
                    BPERM(((ph + 1) & 3) * 64 + bcast_base, __float_as_int(xsrc)));

                const int pA1 = PKRTZ_I(h1f[b][0], h1f[b][1]);
                const int pB1 = PKRTZ_I(h1f[b][2], h1f[b][3]); // q3 hi = pad = 0
                const int pA2 = PKRTZ_I(h2f[b][0], h2f[b][1]);
                const int pB2 = PKRTZ_I(h2f[b][2], h2f[b][3]);
                const int pA3 = PKRTZ_I(h3f[b][0], h3f[b][1]);
                const int pB3 = PKRTZ_I(h3f[b][2], h3f[b][3]);

                // cell1: in = h1_prev (+x at k=27), own = {bias at k=31}
                const int4v v1 = { pA1,
                                   q3 ? PKRTZ_I(h1f[b][2], xv[b]) : pB1,
                                   0,
                                   q3 ? 0x3C000000 : 0 };
                // cell2: in = h1(i-1), own = h2(i-2) (+bias at k=31)
                const int4v v2 = { pA1, pB1, pA2,
                                   q3 ? PKRTZ_I(h2f[b][2], bias2v) : pB2 };
                // cell3: in = h2(i-2), own = h3(i-3) (+bias at k=31)
                const int4v v3 = { pA2, pB2, pA3,
                                   q3 ? PKRTZ_I(h3f[b][2], bias3v) : pB3 };
                B1[b] = __builtin_bit_cast(half8, v1);
                B2[b] = __builtin_bit_cast(half8, v2);
                B3[b] = __builtin_bit_cast(half8, v3);
            }

            // ---- all 24 MFMAs up front: maximal issue-to-read distance ----
            f32x4 D1[2][4], D2[2][4], D3[2][4];
#pragma unroll
            for (int b = 0; b < 2; ++b) {
#pragma unroll
                for (int g = 0; g < 4; ++g) {
                    D1[b][g] = __builtin_amdgcn_mfma_f32_16x16x32_f16(
                        a1[g], B1[b], z4, 0, 0, 0);
                    D2[b][g] = __builtin_amdgcn_mfma_f32_16x16x32_f16(
                        a2[g], B2[b], z4, 0, 0, 0);
                    D3[b][g] = __builtin_amdgcn_mfma_f32_16x16x32_f16(
                        a3[g], B3[b], z4, 0, 0, 0);
                }
            }

            // ---- head (independent; fills MFMA latency shadow) ----
            const int pho = (ph + 1) & 3; // = (i-3)&3
#pragma unroll
            for (int b = 0; b < 2; ++b) {
                float p = fmaf(wl[0], h3f[b][0],
                          fmaf(wl[1], h3f[b][1],
                          fmaf(wl[2], h3f[b][2], wl[3] * h3f[b][3])));
                p += __shfl_xor(p, 16, 64);   // sum across quads (same column n)
                p += __shfl_xor(p, 32, 64);
                ysel[b] = (q == pho) ? (p + blv) : ysel[b];
            }

            // ---- gate math: 6 independent streams ----
#pragma unroll
            for (int b = 0; b < 2; ++b) {
#pragma unroll
                for (int r = 0; r < 4; ++r) {
                    {
                        const float iv = SIGM(D1[b][0][r]);
                        const float fv = SIGM(D1[b][1][r]);
                        const float gv = TANHF(D1[b][2][r]);
                        const float ov = SIGM(D1[b][3][r]);
                        c1f[b][r] = fmaf(fv, c1f[b][r], iv * gv);
                        h1f[b][r] = ov * TANHF(c1f[b][r]);
                    }
                    {
                        const float iv = SIGM(D2[b][0][r]);
                        const float fv = SIGM(D2[b][1][r]);
                        const float gv = TANHF(D2[b][2][r]);
                        const float ov = SIGM(D2[b][3][r]);
                        c2f[b][r] = fmaf(fv, c2f[b][r], iv * gv);
                        h2f[b][r] = ov * TANHF(c2f[b][r]);
                    }
                    {
                        const float iv = SIGM(D3[b][0][r]);
                        const float fv = SIGM(D3[b][1][r]);
                        const float gv = TANHF(D3[b][2][r]);
                        const float ov = SIGM(D3[b][3][r]);
                        c3f[b][r] = fmaf(fv, c3f[b][r], iv * gv);
                        h3f[b][r] = ov * TANHF(c3f[b][r]);
                    }
                }
            }

#pragma unroll
            for (int b = 0; b < 2; ++b) xv[b] = xv_n[b];

            if (ph == 2) {                 // all 4 ysel phases complete here
                if (t0 >= 4) {
#pragma unroll
                    for (int b = 0; b < 2; ++b) orow[b][t0 - 4 + q] = ysel[b];
                }
            }
        }
        // tile advance + prefetch (clamped reads are discarded garbage)
        const int tn = t0 + 8 + q;
        const int tc = (tn < TT) ? tn : q;
#pragma unroll
        for (int b = 0; b < 2; ++b) {
            xtile[b] = xtile_n[b];
            xtile_n[b] = xrow[b][tc];
        }
    }
}

extern "C" void kernel_launch(void* const* d_in, const int* in_sizes, int n_in,
                              void* d_out, int out_size, void* d_ws, size_t ws_size,
                              hipStream_t stream) {
    const float* input = (const float*)d_in[0];
    const float* w_ih1 = (const float*)d_in[1];
    const float* w_hh1 = (const float*)d_in[2];
    const float* b_ih1 = (const float*)d_in[3];
    const float* b_hh1 = (const float*)d_in[4];
    const float* w_ih2 = (const float*)d_in[5];
    const float* w_hh2 = (const float*)d_in[6];
    const float* b_ih2 = (const float*)d_in[7];
    const float* b_hh2 = (const float*)d_in[8];
    const float* w_ih3 = (const float*)d_in[9];
    const float* w_hh3 = (const float*)d_in[10];
    const float* b_ih3 = (const float*)d_in[11];
    const float* b_hh3 = (const float*)d_in[12];
    const float* w_lin = (const float*)d_in[13];
    const float* b_lin = (const float*)d_in[14];
    float* out = (float*)d_out;

    const int B = in_sizes[0] / TT;      // 8192
    const int blocks = B / 32;           // 256 waves, 2x16 elems each

    lstm3_mfma<<<blocks, 64, 0, stream>>>(
        input, w_ih1, w_hh1, b_ih1, b_hh1,
        w_ih2, w_hh2, b_ih2, b_hh2,
        w_ih3, w_hh3, b_ih3, b_hh3,
        w_lin, b_lin, out);
}